// Round 7
// baseline (2843.579 us; speedup 1.0000x reference)
//
#include <hip/hip_runtime.h>
#include <hip/hip_bf16.h>

#define T_ 256
#define B_ 64
#define NWG 32      // recurrence WGs: each owns 16 h-dims

typedef __attribute__((ext_vector_type(8))) short bf16x8;
typedef __attribute__((ext_vector_type(4))) float f32x4;

__device__ __forceinline__ float bf2f(unsigned short u){
  unsigned int i = ((unsigned int)u) << 16;
  float f; __builtin_memcpy(&f, &i, 4); return f;
}
__device__ __forceinline__ unsigned short f2bf(float f){
  __hip_bfloat16 h = __float2bfloat16(f);
  unsigned short u; __builtin_memcpy(&u, &h, 2); return u;
}
__device__ __forceinline__ float sigm(float x){ return 1.0f/(1.0f + expf(-x)); }

// agent-scope (sc-flagged) accessors: per-access coherent, no cache-wide invalidates
__device__ __forceinline__ bf16x8 ld_h8(const unsigned short* p){
  union { unsigned long long q[2]; bf16x8 v; } u;
  u.q[0] = __hip_atomic_load((const unsigned long long*)p,       __ATOMIC_RELAXED, __HIP_MEMORY_SCOPE_AGENT);
  u.q[1] = __hip_atomic_load((const unsigned long long*)(p + 4), __ATOMIC_RELAXED, __HIP_MEMORY_SCOPE_AGENT);
  return u.v;
}
__device__ __forceinline__ void st_h4(unsigned short* p, unsigned short a, unsigned short b,
                                      unsigned short c, unsigned short d){
  unsigned long long v = (unsigned long long)a | ((unsigned long long)b<<16)
                       | ((unsigned long long)c<<32) | ((unsigned long long)d<<48);
  __hip_atomic_store((unsigned long long*)p, v, __ATOMIC_RELAXED, __HIP_MEMORY_SCOPE_AGENT);
}
__device__ __forceinline__ unsigned long long ld_h4(const unsigned short* p){
  return __hip_atomic_load((const unsigned long long*)p, __ATOMIC_RELAXED, __HIP_MEMORY_SCOPE_AGENT);
}

// ---------------- prep ----------------
__global__ void k_prep(const int* __restrict__ in0, const int* __restrict__ in1,
                       const int* __restrict__ mtok,
                       const float* __restrict__ emb0, const float* __restrict__ emb1,
                       const float* __restrict__ Wih_low, const float* __restrict__ Whh_low_f,
                       const float* __restrict__ Wih_high_f, const float* __restrict__ Whh_high_f,
                       const float* __restrict__ Wdec0_f, const float* __restrict__ Wdec1_f,
                       unsigned short* __restrict__ W0, unsigned short* __restrict__ Wlh,
                       unsigned short* __restrict__ Whhl, unsigned short* __restrict__ Wihh,
                       unsigned short* __restrict__ Whhh, unsigned short* __restrict__ Wd0,
                       unsigned short* __restrict__ Wd1, unsigned short* __restrict__ E,
                       float* __restrict__ mask, unsigned* __restrict__ stepflag,
                       unsigned* __restrict__ bar)
{
  int gid = blockIdx.x*blockDim.x + threadIdx.x;
  int gsz = gridDim.x*blockDim.x;
  for (int i=gid; i<2048*512; i+=gsz){
    int r = i>>9, c = i&511;
    W0[i]   = f2bf(Wih_low[(size_t)r*1024 + c]);
    Wlh[i]  = f2bf(Wih_low[(size_t)r*1024 + 512 + c]);
    Whhl[i] = f2bf(Whh_low_f[i]);
    Wihh[i] = f2bf(Wih_high_f[i]);
    Whhh[i] = f2bf(Whh_high_f[i]);
    Wd0[i]  = f2bf(Wdec0_f[i]);
  }
  for (int i=gid; i<512*512; i+=gsz) Wd1[i] = f2bf(Wdec1_f[i]);
  int mt = mtok[0];
  for (int i=gid; i<T_*B_*512; i+=gsz){
    int m = i>>9, k = i&511;
    int t = m>>6, b = m&63;
    float v;
    if (k < 256) v = emb0[(size_t)in0[b*T_+t]*256 + k];
    else         v = emb1[(size_t)in1[b*T_+t]*256 + (k-256)];
    E[i] = f2bf(v);
  }
  for (int i=gid; i<T_*B_; i+=gsz){
    int t = i>>6, b = i&63;
    mask[i] = (in0[b*T_+t] == mt) ? 1.0f : 0.0f;
  }
  for (int i=gid; i<T_; i+=gsz){
    unsigned f = 0;
    for (int b=0;b<B_;b++) f |= (in0[b*T_+i] == mt) ? 1u : 0u;
    stepflag[i] = f;
  }
  if (gid == 0){ bar[0] = 0; bar[32] = 0; }
}

// ---------------- bf16 MFMA GEMM: out[M,N] = A[M,512] @ W[N,512]^T + bias ----------------
__launch_bounds__(256)
__global__ void k_gemm(const unsigned short* __restrict__ A,
                       const unsigned short* __restrict__ W,
                       const float* __restrict__ bias1, const float* __restrict__ bias2,
                       unsigned short* __restrict__ out16, float* __restrict__ out32,
                       int N, int mode)
{
  __shared__ unsigned short As[128*40];
  __shared__ unsigned short Bs[128*40];
  const int tid = threadIdx.x;
  const int m0 = blockIdx.x*128, n0 = blockIdx.y*128;
  const int wid = tid>>6, lane = tid&63;
  const int wm = (wid>>1)*64, wn = (wid&1)*64;
  const int lr = lane&15, lk = lane>>4;
  f32x4 acc[4][4] = {};
  for (int k0=0; k0<512; k0+=32){
    __syncthreads();
    #pragma unroll
    for (int i=0;i<2;i++){
      int eb = tid + 256*i;
      int row = eb>>2, kb = eb&3;
      *(bf16x8*)&As[row*40 + kb*8] = *(const bf16x8*)&A[(size_t)(m0+row)*512 + k0 + kb*8];
      *(bf16x8*)&Bs[row*40 + kb*8] = *(const bf16x8*)&W[(size_t)(n0+row)*512 + k0 + kb*8];
    }
    __syncthreads();
    bf16x8 af[4], bff[4];
    #pragma unroll
    for (int i=0;i<4;i++){
      af[i]  = *(const bf16x8*)&As[(wm + i*16 + lr)*40 + lk*8];
      bff[i] = *(const bf16x8*)&Bs[(wn + i*16 + lr)*40 + lk*8];
    }
    #pragma unroll
    for (int mi=0;mi<4;mi++)
      #pragma unroll
      for (int ni=0;ni<4;ni++)
        acc[mi][ni] = __builtin_amdgcn_mfma_f32_16x16x32_bf16(af[mi], bff[ni], acc[mi][ni], 0,0,0);
  }
  #pragma unroll
  for (int mi=0;mi<4;mi++){
    #pragma unroll
    for (int ni=0;ni<4;ni++){
      int n = n0 + wn + ni*16 + lr;
      float bb = bias1 ? bias1[n] : 0.0f;
      if (bias2) bb += bias2[n];
      #pragma unroll
      for (int r=0;r<4;r++){
        int m = m0 + wm + mi*16 + lk*4 + r;
        float v = acc[mi][ni][r] + bb;
        if (mode == 0){
          out16[(size_t)m*N + n] = f2bf(v);
        } else {
          int t = m>>6, b = m&63;
          out32[((size_t)b*T_ + t)*N + n] = v;
        }
      }
    }
  }
}

// ---------------- grid barrier: counter-arrive + read-only flag spin ----------------
// Arrivals RMW bar[0] once (ACQ_REL). Only the LAST arriver writes bar[32]
// (RELEASE). Spinners poll bar[32] -- a line nobody RMWs -- so polls don't
// contend with the serialized arrive chain (r6's counter-poll did).
__device__ __forceinline__ void gbarrier(unsigned* bar, unsigned gen){
  __syncthreads();
  if (threadIdx.x == 0){
    unsigned old = __hip_atomic_fetch_add(&bar[0], 1u, __ATOMIC_ACQ_REL, __HIP_MEMORY_SCOPE_AGENT);
    if (old == gen*NWG + (NWG-1)){
      __hip_atomic_store(&bar[32], gen+1u, __ATOMIC_RELEASE, __HIP_MEMORY_SCOPE_AGENT);
    } else {
      while (__hip_atomic_load(&bar[32], __ATOMIC_ACQUIRE, __HIP_MEMORY_SCOPE_AGENT) < gen+1u)
        __builtin_amdgcn_s_sleep(1);
    }
  }
  __syncthreads();
}

// hht[b][n] = Wlh_rows(n) . h_h[b,:]  (cached, recomputed only on flagged steps)
__device__ __forceinline__ void compute_hht(const unsigned short* __restrict__ hh,
                                            const unsigned short* __restrict__ Wlh,
                                            float* hht, int d0, int mb, int lr, int lk)
{
  bf16x8 av[16];
  #pragma unroll
  for (int ks=0;ks<16;ks++)
    av[ks] = ld_h8(&hh[(mb+lr)*512 + ks*32 + lk*8]);
  f32x4 a[4] = {};
  #pragma unroll
  for (int ks=0;ks<16;ks++){
    #pragma unroll
    for (int g=0; g<4; g++){
      bf16x8 bg = *(const bf16x8*)&Wlh[(size_t)(g*512 + d0 + lr)*512 + ks*32 + lk*8];
      a[g] = __builtin_amdgcn_mfma_f32_16x16x32_bf16(av[ks], bg, a[g], 0,0,0);
    }
  }
  #pragma unroll
  for (int g=0; g<4; g++)
    #pragma unroll
    for (int r=0;r<4;r++){
      int b = mb + lk*4 + r;
      hht[b*68 + g*16 + lr] = a[g][r];
    }
}

// ---------------- persistent recurrence: 32 WGs, WG j owns h-dims [16j, 16j+16) ----------------
__launch_bounds__(256)
__global__ void k_recur(const float* __restrict__ h_low0, const float* __restrict__ c_low0,
                        const float* __restrict__ h_high0, const float* __restrict__ c_high0,
                        const float* __restrict__ bih_high, const float* __restrict__ bhh_high,
                        const unsigned short* __restrict__ xW,
                        const unsigned short* __restrict__ Whhl,
                        const unsigned short* __restrict__ Wlh,
                        const unsigned short* __restrict__ Wihh,
                        const unsigned short* __restrict__ Whhh,
                        const float* __restrict__ mask, const unsigned* __restrict__ stepflag,
                        unsigned short* __restrict__ hl_buf, unsigned short* __restrict__ hh_buf,
                        unsigned short* __restrict__ hseq, unsigned* bar,
                        float* __restrict__ outS)
{
  __shared__ unsigned short Ws[64*520];   // Whh_low slice (64 gate rows), LDS-resident
  __shared__ float hht[64*68];            // cached W_lh @ h_h term
  __shared__ float gb[64*68];             // gate staging
  __shared__ float cl[64*16];
  __shared__ float ch[64*16];
  const int tid = threadIdx.x;
  const int j = blockIdx.x;
  const int d0 = j*16;
  const int wid = tid>>6, lane = tid&63;
  const int lr = lane&15, lk = lane>>4;
  const int mb = wid*16;
  const int eb = tid>>2;            // batch for elementwise
  const int ep = (tid&3)*4;         // 4 dims per thread

  for (int i=tid; i<64*64; i+=256){
    int n = i>>6, cb = i&63;
    int grow = (n>>4)*512 + d0 + (n&15);
    *(bf16x8*)&Ws[n*520 + cb*8] = *(const bf16x8*)&Whhl[(size_t)grow*512 + cb*8];
  }
  for (int i=tid; i<1024; i+=256){
    int b=i>>4, dd=i&15;
    cl[i] = c_low0[b*512 + d0 + dd];
    ch[i] = c_high0[b*512 + d0 + dd];
  }
  {
    int gi = eb*512 + d0 + ep;
    st_h4(&hl_buf[gi], f2bf(h_low0[gi]), f2bf(h_low0[gi+1]), f2bf(h_low0[gi+2]), f2bf(h_low0[gi+3]));
    st_h4(&hh_buf[gi], f2bf(h_high0[gi]), f2bf(h_high0[gi+1]), f2bf(h_high0[gi+2]), f2bf(h_high0[gi+3]));
  }
  // prefetch xW[0] (independent of h) so its latency hides under the first barrier
  unsigned long long uxi, uxf, uxg, uxo;
  {
    size_t xr = ((size_t)0*64 + eb)*2048 + d0 + ep;
    uxi = *(const unsigned long long*)&xW[xr];
    uxf = *(const unsigned long long*)&xW[xr + 512];
    uxg = *(const unsigned long long*)&xW[xr + 1024];
    uxo = *(const unsigned long long*)&xW[xr + 1536];
  }
  unsigned gen = 0;
  gbarrier(bar, gen); gen++;
  compute_hht(hh_buf, Wlh, hht, d0, mb, lr, lk);
  __syncthreads();

  int hs = 0;
  for (int t=0; t<T_; t++){
    const int rl = t&1, wl = rl^1;
    const unsigned short* hlr = hl_buf + rl*32768;
    // ---- phase A: low cell ----
    bf16x8 av[16];
    #pragma unroll
    for (int ks=0;ks<16;ks++)
      av[ks] = ld_h8(&hlr[(mb+lr)*512 + ks*32 + lk*8]);
    f32x4 a[4] = {};
    #pragma unroll
    for (int ks=0;ks<16;ks++){
      #pragma unroll
      for (int g=0; g<4; g++){
        bf16x8 bg = *(const bf16x8*)&Ws[(g*16+lr)*520 + ks*32 + lk*8];
        a[g] = __builtin_amdgcn_mfma_f32_16x16x32_bf16(av[ks], bg, a[g], 0,0,0);
      }
    }
    #pragma unroll
    for (int g=0; g<4; g++)
      #pragma unroll
      for (int r=0;r<4;r++){
        int b = mb + lk*4 + r;
        gb[b*68 + g*16 + lr] = a[g][r] + hht[b*68 + g*16 + lr];
      }
    __syncthreads();
    {
      const int b = eb;
      unsigned short hb[4];
      #pragma unroll
      for (int q=0;q<4;q++){
        int dd = ep + q;
        float g_i = gb[b*68 + dd]      + bf2f((unsigned short)(uxi >> (16*q)));
        float g_f = gb[b*68 + 16 + dd] + bf2f((unsigned short)(uxf >> (16*q)));
        float g_g = gb[b*68 + 32 + dd] + bf2f((unsigned short)(uxg >> (16*q)));
        float g_o = gb[b*68 + 48 + dd] + bf2f((unsigned short)(uxo >> (16*q)));
        float c = sigm(g_f)*cl[b*16+dd] + sigm(g_i)*tanhf(g_g);
        float h = sigm(g_o)*tanhf(c);
        cl[b*16+dd] = c;
        hb[q] = f2bf(h);
      }
      st_h4(&hl_buf[wl*32768 + b*512 + d0 + ep], hb[0], hb[1], hb[2], hb[3]);
      unsigned long long hp = (unsigned long long)hb[0] | ((unsigned long long)hb[1]<<16)
                            | ((unsigned long long)hb[2]<<32) | ((unsigned long long)hb[3]<<48);
      *(unsigned long long*)&hseq[((size_t)t*64 + b)*512 + d0 + ep] = hp;
    }
    // prefetch next step's xW before the barrier: latency hides under the spin
    if (t+1 < T_){
      size_t xr = ((size_t)(t+1)*64 + eb)*2048 + d0 + ep;
      uxi = *(const unsigned long long*)&xW[xr];
      uxf = *(const unsigned long long*)&xW[xr + 512];
      uxg = *(const unsigned long long*)&xW[xr + 1024];
      uxo = *(const unsigned long long*)&xW[xr + 1536];
    }
    gbarrier(bar, gen); gen++;
    // ---- phase B: high cell (only ~8/256 steps) ----
    if (stepflag[t]){
      const unsigned short* hln = hl_buf + wl*32768;
      const unsigned short* hhr = hh_buf + hs*32768;
      bf16x8 avl[16], avh[16];
      #pragma unroll
      for (int ks=0;ks<16;ks++){
        avl[ks] = ld_h8(&hln[(mb+lr)*512 + ks*32 + lk*8]);
        avh[ks] = ld_h8(&hhr[(mb+lr)*512 + ks*32 + lk*8]);
      }
      f32x4 hacc[4] = {};
      #pragma unroll
      for (int ks=0;ks<16;ks++){
        #pragma unroll
        for (int g=0; g<4; g++){
          size_t grw = (size_t)(g*512 + d0 + lr)*512 + ks*32 + lk*8;
          bf16x8 bi = *(const bf16x8*)&Wihh[grw];
          bf16x8 bh = *(const bf16x8*)&Whhh[grw];
          hacc[g] = __builtin_amdgcn_mfma_f32_16x16x32_bf16(avl[ks], bi, hacc[g], 0,0,0);
          hacc[g] = __builtin_amdgcn_mfma_f32_16x16x32_bf16(avh[ks], bh, hacc[g], 0,0,0);
        }
      }
      #pragma unroll
      for (int g=0; g<4; g++)
        #pragma unroll
        for (int r=0;r<4;r++){
          int b = mb + lk*4 + r;
          gb[b*68 + g*16 + lr] = hacc[g][r];
        }
      __syncthreads();
      {
        const int b = eb;
        float m = mask[t*64 + b];
        unsigned long long hold4 = ld_h4(&hh_buf[hs*32768 + b*512 + d0 + ep]);
        unsigned short hn[4];
        #pragma unroll
        for (int q=0;q<4;q++){
          int dd = ep + q; int d = d0 + dd;
          float g_i = gb[b*68+dd]      + bih_high[d]      + bhh_high[d];
          float g_f = gb[b*68+16+dd]   + bih_high[512+d]  + bhh_high[512+d];
          float g_g = gb[b*68+32+dd]   + bih_high[1024+d] + bhh_high[1024+d];
          float g_o = gb[b*68+48+dd]   + bih_high[1536+d] + bhh_high[1536+d];
          float ct = sigm(g_f)*ch[b*16+dd] + sigm(g_i)*tanhf(g_g);
          float ht = sigm(g_o)*tanhf(ct);
          float hold = bf2f((unsigned short)(hold4 >> (16*q)));
          hn[q] = f2bf(m*ht + (1.0f-m)*hold);
          ch[b*16+dd] = m*ct + (1.0f-m)*ch[b*16+dd];
        }
        st_h4(&hh_buf[(hs^1)*32768 + b*512 + d0 + ep], hn[0], hn[1], hn[2], hn[3]);
      }
      gbarrier(bar, gen); gen++;
      hs ^= 1;
      compute_hht(hh_buf + hs*32768, Wlh, hht, d0, mb, lr, lk);
      __syncthreads();
    }
  }
  // final states -> f32 (h_l in slot 0 after t=255)
  {
    int gi = eb*512 + d0 + ep;
    unsigned long long hl4 = ld_h4(&hl_buf[gi]);
    unsigned long long hh4 = ld_h4(&hh_buf[hs*32768 + gi]);
    #pragma unroll
    for (int q=0;q<4;q++){
      outS[gi+q]           = bf2f((unsigned short)(hl4 >> (16*q)));
      outS[32768 + gi + q] = cl[eb*16 + ep + q];
      outS[65536 + gi + q] = bf2f((unsigned short)(hh4 >> (16*q)));
      outS[98304 + gi + q] = ch[eb*16 + ep + q];
    }
  }
}

extern "C" void kernel_launch(void* const* d_in, const int* in_sizes, int n_in,
                              void* d_out, int out_size, void* d_ws, size_t ws_size,
                              hipStream_t stream)
{
  const int*   in0    = (const int*)  d_in[0];
  const int*   in1    = (const int*)  d_in[1];
  const float* hl0    = (const float*)d_in[2];
  const float* cl0    = (const float*)d_in[3];
  const float* hh0    = (const float*)d_in[4];
  const float* ch0    = (const float*)d_in[5];
  const int*   mtok   = (const int*)  d_in[6];
  const float* emb0   = (const float*)d_in[7];
  const float* emb1   = (const float*)d_in[8];
  const float* Wihl_f = (const float*)d_in[9];
  const float* bihl   = (const float*)d_in[10];
  const float* Whhl_f = (const float*)d_in[11];
  const float* bhhl   = (const float*)d_in[12];
  const float* Wihh_f = (const float*)d_in[13];
  const float* bihh   = (const float*)d_in[14];
  const float* Whhh_f = (const float*)d_in[15];
  const float* bhhh   = (const float*)d_in[16];
  const float* Wd0_f  = (const float*)d_in[17];
  const float* bd0    = (const float*)d_in[18];
  const float* Wd1_f  = (const float*)d_in[19];
  const float* bd1    = (const float*)d_in[20];

  // d_out is FLOAT. Layout (floats): dec0 [B,T,2048] @0, dec1 [B,T,512] @33554432,
  // states @41943040 (4 x 32768).
  float* dout = (float*)d_out;
  // bf16 scratch aliased into d_out (dead before the dec GEMMs write there)
  unsigned short* xW = (unsigned short*)dout;              // 64 MiB in dec0 region
  unsigned short* E  = (unsigned short*)(dout + 33554432); // 16 MiB in dec1 region

  char* ws = (char*)d_ws;
  unsigned short* hseq = (unsigned short*)(ws + 0);          // [16384][512] bf16, 16 MiB
  unsigned short* W0   = (unsigned short*)(ws + 16777216);
  unsigned short* Wlh  = (unsigned short*)(ws + 18874368);
  unsigned short* Whhl = (unsigned short*)(ws + 20971520);
  unsigned short* Wihh = (unsigned short*)(ws + 23068672);
  unsigned short* Whhh = (unsigned short*)(ws + 25165824);
  unsigned short* Wd0  = (unsigned short*)(ws + 27262976);
  unsigned short* Wd1  = (unsigned short*)(ws + 29360128);
  unsigned short* hlb  = (unsigned short*)(ws + 29884416);   // [2][64][512] bf16
  unsigned short* hhb  = (unsigned short*)(ws + 30015488);   // [2][64][512] bf16
  float*          mask = (float*)    (ws + 30146560);        // [256][64]
  unsigned*       sflg = (unsigned*) (ws + 30212096);        // [256]
  unsigned*       bar  = (unsigned*) (ws + 30213120);

  k_prep<<<2048, 256, 0, stream>>>(in0,in1,mtok,emb0,emb1,Wihl_f,Whhl_f,Wihh_f,Whhh_f,Wd0_f,Wd1_f,
                                   W0,Wlh,Whhl,Wihh,Whhh,Wd0,Wd1,E,mask,sflg,bar);
  dim3 g1(128,16);
  k_gemm<<<g1, 256, 0, stream>>>(E, W0, bihl, bhhl, xW, nullptr, 2048, 0);
  k_recur<<<NWG, 256, 0, stream>>>(hl0,cl0,hh0,ch0,bihh,bhhh,xW,Whhl,Wlh,Wihh,Whhh,
                                   mask,sflg,hlb,hhb,hseq,bar,dout + 41943040);
  k_gemm<<<g1, 256, 0, stream>>>(hseq, Wd0, bd0, nullptr, nullptr, dout, 2048, 1);
  dim3 g2(128,4);
  k_gemm<<<g2, 256, 0, stream>>>(hseq, Wd1, bd1, nullptr, nullptr, dout + 33554432, 512, 1);
}

// Round 8
// 2398.327 us; speedup vs baseline: 1.1857x; 1.1857x over previous
//
#include <hip/hip_runtime.h>
#include <hip/hip_bf16.h>

#define T_ 256
#define B_ 64
#define NWG 32      // recurrence WGs: each owns 16 h-dims

typedef __attribute__((ext_vector_type(8))) short bf16x8;
typedef __attribute__((ext_vector_type(4))) float f32x4;

__device__ __forceinline__ float bf2f(unsigned short u){
  unsigned int i = ((unsigned int)u) << 16;
  float f; __builtin_memcpy(&f, &i, 4); return f;
}
__device__ __forceinline__ unsigned short f2bf(float f){
  __hip_bfloat16 h = __float2bfloat16(f);
  unsigned short u; __builtin_memcpy(&u, &h, 2); return u;
}
__device__ __forceinline__ float sigm(float x){ return 1.0f/(1.0f + expf(-x)); }

// agent-scope (sc-flagged) accessors: execute at the coherence point.
// RELAXED only -- acquire/release variants emit buffer_inv / buffer_wbl2
// (L2-wide maintenance) on gfx950, which was r5's 140ms disaster and r6/r7's
// residual ~10us/barrier.
__device__ __forceinline__ bf16x8 ld_h8(const unsigned short* p){
  union { unsigned long long q[2]; bf16x8 v; } u;
  u.q[0] = __hip_atomic_load((const unsigned long long*)p,       __ATOMIC_RELAXED, __HIP_MEMORY_SCOPE_AGENT);
  u.q[1] = __hip_atomic_load((const unsigned long long*)(p + 4), __ATOMIC_RELAXED, __HIP_MEMORY_SCOPE_AGENT);
  return u.v;
}
__device__ __forceinline__ void st_h4(unsigned short* p, unsigned short a, unsigned short b,
                                      unsigned short c, unsigned short d){
  unsigned long long v = (unsigned long long)a | ((unsigned long long)b<<16)
                       | ((unsigned long long)c<<32) | ((unsigned long long)d<<48);
  __hip_atomic_store((unsigned long long*)p, v, __ATOMIC_RELAXED, __HIP_MEMORY_SCOPE_AGENT);
}
__device__ __forceinline__ unsigned long long ld_h4(const unsigned short* p){
  return __hip_atomic_load((const unsigned long long*)p, __ATOMIC_RELAXED, __HIP_MEMORY_SCOPE_AGENT);
}

// ---------------- prep ----------------
__global__ void k_prep(const int* __restrict__ in0, const int* __restrict__ in1,
                       const int* __restrict__ mtok,
                       const float* __restrict__ emb0, const float* __restrict__ emb1,
                       const float* __restrict__ Wih_low, const float* __restrict__ Whh_low_f,
                       const float* __restrict__ Wih_high_f, const float* __restrict__ Whh_high_f,
                       const float* __restrict__ Wdec0_f, const float* __restrict__ Wdec1_f,
                       unsigned short* __restrict__ W0, unsigned short* __restrict__ Wlh,
                       unsigned short* __restrict__ Whhl, unsigned short* __restrict__ Wihh,
                       unsigned short* __restrict__ Whhh, unsigned short* __restrict__ Wd0,
                       unsigned short* __restrict__ Wd1, unsigned short* __restrict__ E,
                       float* __restrict__ mask, unsigned* __restrict__ stepflag,
                       unsigned* __restrict__ bar)
{
  int gid = blockIdx.x*blockDim.x + threadIdx.x;
  int gsz = gridDim.x*blockDim.x;
  for (int i=gid; i<2048*512; i+=gsz){
    int r = i>>9, c = i&511;
    W0[i]   = f2bf(Wih_low[(size_t)r*1024 + c]);
    Wlh[i]  = f2bf(Wih_low[(size_t)r*1024 + 512 + c]);
    Whhl[i] = f2bf(Whh_low_f[i]);
    Wihh[i] = f2bf(Wih_high_f[i]);
    Whhh[i] = f2bf(Whh_high_f[i]);
    Wd0[i]  = f2bf(Wdec0_f[i]);
  }
  for (int i=gid; i<512*512; i+=gsz) Wd1[i] = f2bf(Wdec1_f[i]);
  int mt = mtok[0];
  for (int i=gid; i<T_*B_*512; i+=gsz){
    int m = i>>9, k = i&511;
    int t = m>>6, b = m&63;
    float v;
    if (k < 256) v = emb0[(size_t)in0[b*T_+t]*256 + k];
    else         v = emb1[(size_t)in1[b*T_+t]*256 + (k-256)];
    E[i] = f2bf(v);
  }
  for (int i=gid; i<T_*B_; i+=gsz){
    int t = i>>6, b = i&63;
    mask[i] = (in0[b*T_+t] == mt) ? 1.0f : 0.0f;
  }
  for (int i=gid; i<T_; i+=gsz){
    unsigned f = 0;
    for (int b=0;b<B_;b++) f |= (in0[b*T_+i] == mt) ? 1u : 0u;
    stepflag[i] = f;
  }
  if (gid == 0){ bar[0] = 0; bar[32] = 0; }
}

// ---------------- bf16 MFMA GEMM: out[M,N] = A[M,512] @ W[N,512]^T + bias ----------------
__launch_bounds__(256)
__global__ void k_gemm(const unsigned short* __restrict__ A,
                       const unsigned short* __restrict__ W,
                       const float* __restrict__ bias1, const float* __restrict__ bias2,
                       unsigned short* __restrict__ out16, float* __restrict__ out32,
                       int N, int mode)
{
  __shared__ unsigned short As[128*40];
  __shared__ unsigned short Bs[128*40];
  const int tid = threadIdx.x;
  const int m0 = blockIdx.x*128, n0 = blockIdx.y*128;
  const int wid = tid>>6, lane = tid&63;
  const int wm = (wid>>1)*64, wn = (wid&1)*64;
  const int lr = lane&15, lk = lane>>4;
  f32x4 acc[4][4] = {};
  for (int k0=0; k0<512; k0+=32){
    __syncthreads();
    #pragma unroll
    for (int i=0;i<2;i++){
      int eb = tid + 256*i;
      int row = eb>>2, kb = eb&3;
      *(bf16x8*)&As[row*40 + kb*8] = *(const bf16x8*)&A[(size_t)(m0+row)*512 + k0 + kb*8];
      *(bf16x8*)&Bs[row*40 + kb*8] = *(const bf16x8*)&W[(size_t)(n0+row)*512 + k0 + kb*8];
    }
    __syncthreads();
    bf16x8 af[4], bff[4];
    #pragma unroll
    for (int i=0;i<4;i++){
      af[i]  = *(const bf16x8*)&As[(wm + i*16 + lr)*40 + lk*8];
      bff[i] = *(const bf16x8*)&Bs[(wn + i*16 + lr)*40 + lk*8];
    }
    #pragma unroll
    for (int mi=0;mi<4;mi++)
      #pragma unroll
      for (int ni=0;ni<4;ni++)
        acc[mi][ni] = __builtin_amdgcn_mfma_f32_16x16x32_bf16(af[mi], bff[ni], acc[mi][ni], 0,0,0);
  }
  #pragma unroll
  for (int mi=0;mi<4;mi++){
    #pragma unroll
    for (int ni=0;ni<4;ni++){
      int n = n0 + wn + ni*16 + lr;
      float bb = bias1 ? bias1[n] : 0.0f;
      if (bias2) bb += bias2[n];
      #pragma unroll
      for (int r=0;r<4;r++){
        int m = m0 + wm + mi*16 + lk*4 + r;
        float v = acc[mi][ni][r] + bb;
        if (mode == 0){
          out16[(size_t)m*N + n] = f2bf(v);
        } else {
          int t = m>>6, b = m&63;
          out32[((size_t)b*T_ + t)*N + n] = v;
        }
      }
    }
  }
}

// ---------------- grid barrier: ALL-RELAXED (no buffer_inv / buffer_wbl2) ----------------
// Ordering without maintenance ops:
//  - arrive side: __syncthreads() drains vmcnt(0) so this WG's (coherent-point)
//    data stores are complete before the arrive-RMW is issued.
//  - release side: last arriver writes the flag (coherent point).
//  - consume side: post-spin loads are control-dependent on the flag load;
//    sched_barrier(0) stops compiler speculation across the spin.
//  - all cross-WG data is read via sc-flagged atomics (coherence point), so no
//    cache invalidation is ever needed.
__device__ __forceinline__ void gbarrier(unsigned* bar, unsigned gen){
  __syncthreads();
  if (threadIdx.x == 0){
    unsigned old = __hip_atomic_fetch_add(&bar[0], 1u, __ATOMIC_RELAXED, __HIP_MEMORY_SCOPE_AGENT);
    if (old == gen*NWG + (NWG-1)){
      __hip_atomic_store(&bar[32], gen+1u, __ATOMIC_RELAXED, __HIP_MEMORY_SCOPE_AGENT);
    } else {
      while (__hip_atomic_load(&bar[32], __ATOMIC_RELAXED, __HIP_MEMORY_SCOPE_AGENT) < gen+1u)
        __builtin_amdgcn_s_sleep(1);
    }
  }
  __builtin_amdgcn_sched_barrier(0);
  __syncthreads();
  __builtin_amdgcn_sched_barrier(0);
}

// hht[b][n] = Wlh_rows(n) . h_h[b,:]  (cached, recomputed only on flagged steps)
__device__ __forceinline__ void compute_hht(const unsigned short* __restrict__ hh,
                                            const unsigned short* __restrict__ Wlh,
                                            float* hht, int d0, int mb, int lr, int lk)
{
  bf16x8 av[16];
  #pragma unroll
  for (int ks=0;ks<16;ks++)
    av[ks] = ld_h8(&hh[(mb+lr)*512 + ks*32 + lk*8]);
  f32x4 a[4] = {};
  #pragma unroll
  for (int ks=0;ks<16;ks++){
    #pragma unroll
    for (int g=0; g<4; g++){
      bf16x8 bg = *(const bf16x8*)&Wlh[(size_t)(g*512 + d0 + lr)*512 + ks*32 + lk*8];
      a[g] = __builtin_amdgcn_mfma_f32_16x16x32_bf16(av[ks], bg, a[g], 0,0,0);
    }
  }
  #pragma unroll
  for (int g=0; g<4; g++)
    #pragma unroll
    for (int r=0;r<4;r++){
      int b = mb + lk*4 + r;
      hht[b*68 + g*16 + lr] = a[g][r];
    }
}

// ---------------- persistent recurrence: 32 WGs, WG j owns h-dims [16j, 16j+16) ----------------
__launch_bounds__(256)
__global__ void k_recur(const float* __restrict__ h_low0, const float* __restrict__ c_low0,
                        const float* __restrict__ h_high0, const float* __restrict__ c_high0,
                        const float* __restrict__ bih_high, const float* __restrict__ bhh_high,
                        const unsigned short* __restrict__ xW,
                        const unsigned short* __restrict__ Whhl,
                        const unsigned short* __restrict__ Wlh,
                        const unsigned short* __restrict__ Wihh,
                        const unsigned short* __restrict__ Whhh,
                        const float* __restrict__ mask, const unsigned* __restrict__ stepflag,
                        unsigned short* __restrict__ hl_buf, unsigned short* __restrict__ hh_buf,
                        unsigned short* __restrict__ hseq, unsigned* bar,
                        float* __restrict__ outS)
{
  __shared__ unsigned short Ws[64*520];   // Whh_low slice (64 gate rows), LDS-resident
  __shared__ float hht[64*68];            // cached W_lh @ h_h term
  __shared__ float gb[64*68];             // gate staging
  __shared__ float cl[64*16];
  __shared__ float ch[64*16];
  const int tid = threadIdx.x;
  const int j = blockIdx.x;
  const int d0 = j*16;
  const int wid = tid>>6, lane = tid&63;
  const int lr = lane&15, lk = lane>>4;
  const int mb = wid*16;
  const int eb = tid>>2;            // batch for elementwise
  const int ep = (tid&3)*4;         // 4 dims per thread

  for (int i=tid; i<64*64; i+=256){
    int n = i>>6, cb = i&63;
    int grow = (n>>4)*512 + d0 + (n&15);
    *(bf16x8*)&Ws[n*520 + cb*8] = *(const bf16x8*)&Whhl[(size_t)grow*512 + cb*8];
  }
  for (int i=tid; i<1024; i+=256){
    int b=i>>4, dd=i&15;
    cl[i] = c_low0[b*512 + d0 + dd];
    ch[i] = c_high0[b*512 + d0 + dd];
  }
  {
    int gi = eb*512 + d0 + ep;
    st_h4(&hl_buf[gi], f2bf(h_low0[gi]), f2bf(h_low0[gi+1]), f2bf(h_low0[gi+2]), f2bf(h_low0[gi+3]));
    st_h4(&hh_buf[gi], f2bf(h_high0[gi]), f2bf(h_high0[gi+1]), f2bf(h_high0[gi+2]), f2bf(h_high0[gi+3]));
  }
  // prefetch xW[0]: latency hides under the first barrier
  unsigned long long uxi, uxf, uxg, uxo;
  {
    size_t xr = ((size_t)0*64 + eb)*2048 + d0 + ep;
    uxi = *(const unsigned long long*)&xW[xr];
    uxf = *(const unsigned long long*)&xW[xr + 512];
    uxg = *(const unsigned long long*)&xW[xr + 1024];
    uxo = *(const unsigned long long*)&xW[xr + 1536];
  }
  unsigned gen = 0;
  gbarrier(bar, gen); gen++;
  compute_hht(hh_buf, Wlh, hht, d0, mb, lr, lk);
  __syncthreads();

  int hs = 0;
  for (int t=0; t<T_; t++){
    const int rl = t&1, wl = rl^1;
    const unsigned short* hlr = hl_buf + rl*32768;
    // ---- phase A: low cell ----
    bf16x8 av[16];
    #pragma unroll
    for (int ks=0;ks<16;ks++)
      av[ks] = ld_h8(&hlr[(mb+lr)*512 + ks*32 + lk*8]);
    f32x4 a[4] = {};
    #pragma unroll
    for (int ks=0;ks<16;ks++){
      #pragma unroll
      for (int g=0; g<4; g++){
        bf16x8 bg = *(const bf16x8*)&Ws[(g*16+lr)*520 + ks*32 + lk*8];
        a[g] = __builtin_amdgcn_mfma_f32_16x16x32_bf16(av[ks], bg, a[g], 0,0,0);
      }
    }
    #pragma unroll
    for (int g=0; g<4; g++)
      #pragma unroll
      for (int r=0;r<4;r++){
        int b = mb + lk*4 + r;
        gb[b*68 + g*16 + lr] = a[g][r] + hht[b*68 + g*16 + lr];
      }
    __syncthreads();
    {
      const int b = eb;
      unsigned short hb[4];
      #pragma unroll
      for (int q=0;q<4;q++){
        int dd = ep + q;
        float g_i = gb[b*68 + dd]      + bf2f((unsigned short)(uxi >> (16*q)));
        float g_f = gb[b*68 + 16 + dd] + bf2f((unsigned short)(uxf >> (16*q)));
        float g_g = gb[b*68 + 32 + dd] + bf2f((unsigned short)(uxg >> (16*q)));
        float g_o = gb[b*68 + 48 + dd] + bf2f((unsigned short)(uxo >> (16*q)));
        float c = sigm(g_f)*cl[b*16+dd] + sigm(g_i)*tanhf(g_g);
        float h = sigm(g_o)*tanhf(c);
        cl[b*16+dd] = c;
        hb[q] = f2bf(h);
      }
      st_h4(&hl_buf[wl*32768 + b*512 + d0 + ep], hb[0], hb[1], hb[2], hb[3]);
      unsigned long long hp = (unsigned long long)hb[0] | ((unsigned long long)hb[1]<<16)
                            | ((unsigned long long)hb[2]<<32) | ((unsigned long long)hb[3]<<48);
      *(unsigned long long*)&hseq[((size_t)t*64 + b)*512 + d0 + ep] = hp;
    }
    // prefetch next step's xW before the barrier
    if (t+1 < T_){
      size_t xr = ((size_t)(t+1)*64 + eb)*2048 + d0 + ep;
      uxi = *(const unsigned long long*)&xW[xr];
      uxf = *(const unsigned long long*)&xW[xr + 512];
      uxg = *(const unsigned long long*)&xW[xr + 1024];
      uxo = *(const unsigned long long*)&xW[xr + 1536];
    }
    gbarrier(bar, gen); gen++;
    // ---- phase B: high cell (only ~8/256 steps) ----
    if (stepflag[t]){
      const unsigned short* hln = hl_buf + wl*32768;
      const unsigned short* hhr = hh_buf + hs*32768;
      bf16x8 avl[16], avh[16];
      #pragma unroll
      for (int ks=0;ks<16;ks++){
        avl[ks] = ld_h8(&hln[(mb+lr)*512 + ks*32 + lk*8]);
        avh[ks] = ld_h8(&hhr[(mb+lr)*512 + ks*32 + lk*8]);
      }
      f32x4 hacc[4] = {};
      #pragma unroll
      for (int ks=0;ks<16;ks++){
        #pragma unroll
        for (int g=0; g<4; g++){
          size_t grw = (size_t)(g*512 + d0 + lr)*512 + ks*32 + lk*8;
          bf16x8 bi = *(const bf16x8*)&Wihh[grw];
          bf16x8 bh = *(const bf16x8*)&Whhh[grw];
          hacc[g] = __builtin_amdgcn_mfma_f32_16x16x32_bf16(avl[ks], bi, hacc[g], 0,0,0);
          hacc[g] = __builtin_amdgcn_mfma_f32_16x16x32_bf16(avh[ks], bh, hacc[g], 0,0,0);
        }
      }
      #pragma unroll
      for (int g=0; g<4; g++)
        #pragma unroll
        for (int r=0;r<4;r++){
          int b = mb + lk*4 + r;
          gb[b*68 + g*16 + lr] = hacc[g][r];
        }
      __syncthreads();
      {
        const int b = eb;
        float m = mask[t*64 + b];
        unsigned long long hold4 = ld_h4(&hh_buf[hs*32768 + b*512 + d0 + ep]);
        unsigned short hn[4];
        #pragma unroll
        for (int q=0;q<4;q++){
          int dd = ep + q; int d = d0 + dd;
          float g_i = gb[b*68+dd]      + bih_high[d]      + bhh_high[d];
          float g_f = gb[b*68+16+dd]   + bih_high[512+d]  + bhh_high[512+d];
          float g_g = gb[b*68+32+dd]   + bih_high[1024+d] + bhh_high[1024+d];
          float g_o = gb[b*68+48+dd]   + bih_high[1536+d] + bhh_high[1536+d];
          float ct = sigm(g_f)*ch[b*16+dd] + sigm(g_i)*tanhf(g_g);
          float ht = sigm(g_o)*tanhf(ct);
          float hold = bf2f((unsigned short)(hold4 >> (16*q)));
          hn[q] = f2bf(m*ht + (1.0f-m)*hold);
          ch[b*16+dd] = m*ct + (1.0f-m)*ch[b*16+dd];
        }
        st_h4(&hh_buf[(hs^1)*32768 + b*512 + d0 + ep], hn[0], hn[1], hn[2], hn[3]);
      }
      gbarrier(bar, gen); gen++;
      hs ^= 1;
      compute_hht(hh_buf + hs*32768, Wlh, hht, d0, mb, lr, lk);
      __syncthreads();
    }
  }
  // final states -> f32 (h_l in slot 0 after t=255)
  {
    int gi = eb*512 + d0 + ep;
    unsigned long long hl4 = ld_h4(&hl_buf[gi]);
    unsigned long long hh4 = ld_h4(&hh_buf[hs*32768 + gi]);
    #pragma unroll
    for (int q=0;q<4;q++){
      outS[gi+q]           = bf2f((unsigned short)(hl4 >> (16*q)));
      outS[32768 + gi + q] = cl[eb*16 + ep + q];
      outS[65536 + gi + q] = bf2f((unsigned short)(hh4 >> (16*q)));
      outS[98304 + gi + q] = ch[eb*16 + ep + q];
    }
  }
}

extern "C" void kernel_launch(void* const* d_in, const int* in_sizes, int n_in,
                              void* d_out, int out_size, void* d_ws, size_t ws_size,
                              hipStream_t stream)
{
  const int*   in0    = (const int*)  d_in[0];
  const int*   in1    = (const int*)  d_in[1];
  const float* hl0    = (const float*)d_in[2];
  const float* cl0    = (const float*)d_in[3];
  const float* hh0    = (const float*)d_in[4];
  const float* ch0    = (const float*)d_in[5];
  const int*   mtok   = (const int*)  d_in[6];
  const float* emb0   = (const float*)d_in[7];
  const float* emb1   = (const float*)d_in[8];
  const float* Wihl_f = (const float*)d_in[9];
  const float* bihl   = (const float*)d_in[10];
  const float* Whhl_f = (const float*)d_in[11];
  const float* bhhl   = (const float*)d_in[12];
  const float* Wihh_f = (const float*)d_in[13];
  const float* bihh   = (const float*)d_in[14];
  const float* Whhh_f = (const float*)d_in[15];
  const float* bhhh   = (const float*)d_in[16];
  const float* Wd0_f  = (const float*)d_in[17];
  const float* bd0    = (const float*)d_in[18];
  const float* Wd1_f  = (const float*)d_in[19];
  const float* bd1    = (const float*)d_in[20];

  // d_out is FLOAT. Layout (floats): dec0 [B,T,2048] @0, dec1 [B,T,512] @33554432,
  // states @41943040 (4 x 32768).
  float* dout = (float*)d_out;
  // bf16 scratch aliased into d_out (dead before the dec GEMMs write there)
  unsigned short* xW = (unsigned short*)dout;              // 64 MiB in dec0 region
  unsigned short* E  = (unsigned short*)(dout + 33554432); // 16 MiB in dec1 region

  char* ws = (char*)d_ws;
  unsigned short* hseq = (unsigned short*)(ws + 0);          // [16384][512] bf16, 16 MiB
  unsigned short* W0   = (unsigned short*)(ws + 16777216);
  unsigned short* Wlh  = (unsigned short*)(ws + 18874368);
  unsigned short* Whhl = (unsigned short*)(ws + 20971520);
  unsigned short* Wihh = (unsigned short*)(ws + 23068672);
  unsigned short* Whhh = (unsigned short*)(ws + 25165824);
  unsigned short* Wd0  = (unsigned short*)(ws + 27262976);
  unsigned short* Wd1  = (unsigned short*)(ws + 29360128);
  unsigned short* hlb  = (unsigned short*)(ws + 29884416);   // [2][64][512] bf16
  unsigned short* hhb  = (unsigned short*)(ws + 30015488);   // [2][64][512] bf16
  float*          mask = (float*)    (ws + 30146560);        // [256][64]
  unsigned*       sflg = (unsigned*) (ws + 30212096);        // [256]
  unsigned*       bar  = (unsigned*) (ws + 30213120);

  k_prep<<<2048, 256, 0, stream>>>(in0,in1,mtok,emb0,emb1,Wihl_f,Whhl_f,Wihh_f,Whhh_f,Wd0_f,Wd1_f,
                                   W0,Wlh,Whhl,Wihh,Whhh,Wd0,Wd1,E,mask,sflg,bar);
  dim3 g1(128,16);
  k_gemm<<<g1, 256, 0, stream>>>(E, W0, bihl, bhhl, xW, nullptr, 2048, 0);
  k_recur<<<NWG, 256, 0, stream>>>(hl0,cl0,hh0,ch0,bihh,bhhh,xW,Whhl,Wlh,Wihh,Whhh,
                                   mask,sflg,hlb,hhb,hseq,bar,dout + 41943040);
  k_gemm<<<g1, 256, 0, stream>>>(hseq, Wd0, bd0, nullptr, nullptr, dout, 2048, 1);
  dim3 g2(128,4);
  k_gemm<<<g2, 256, 0, stream>>>(hseq, Wd1, bd1, nullptr, nullptr, dout + 33554432, 512, 1);
}

// Round 9
// 2241.770 us; speedup vs baseline: 1.2685x; 1.0698x over previous
//
#include <hip/hip_runtime.h>
#include <hip/hip_bf16.h>

#define T_ 256
#define B_ 64
#define NWG 32      // recurrence WGs: each owns 16 h-dims

typedef __attribute__((ext_vector_type(8))) short bf16x8;
typedef __attribute__((ext_vector_type(4))) float f32x4;

__device__ __forceinline__ float bf2f(unsigned short u){
  unsigned int i = ((unsigned int)u) << 16;
  float f; __builtin_memcpy(&f, &i, 4); return f;
}
__device__ __forceinline__ unsigned short f2bf(float f){
  __hip_bfloat16 h = __float2bfloat16(f);
  unsigned short u; __builtin_memcpy(&u, &h, 2); return u;
}
__device__ __forceinline__ float sigm(float x){ return 1.0f/(1.0f + expf(-x)); }

// agent-scope (sc-flagged) accessors: execute at the coherence point. RELAXED only.
__device__ __forceinline__ bf16x8 ld_h8(const unsigned short* p){
  union { unsigned long long q[2]; bf16x8 v; } u;
  u.q[0] = __hip_atomic_load((const unsigned long long*)p,       __ATOMIC_RELAXED, __HIP_MEMORY_SCOPE_AGENT);
  u.q[1] = __hip_atomic_load((const unsigned long long*)(p + 4), __ATOMIC_RELAXED, __HIP_MEMORY_SCOPE_AGENT);
  return u.v;
}
__device__ __forceinline__ void st_h4(unsigned short* p, unsigned short a, unsigned short b,
                                      unsigned short c, unsigned short d){
  unsigned long long v = (unsigned long long)a | ((unsigned long long)b<<16)
                       | ((unsigned long long)c<<32) | ((unsigned long long)d<<48);
  __hip_atomic_store((unsigned long long*)p, v, __ATOMIC_RELAXED, __HIP_MEMORY_SCOPE_AGENT);
}
__device__ __forceinline__ unsigned long long ld_h4(const unsigned short* p){
  return __hip_atomic_load((const unsigned long long*)p, __ATOMIC_RELAXED, __HIP_MEMORY_SCOPE_AGENT);
}

// ---------------- prep ----------------
__global__ void k_prep(const int* __restrict__ in0, const int* __restrict__ in1,
                       const int* __restrict__ mtok,
                       const float* __restrict__ emb0, const float* __restrict__ emb1,
                       const float* __restrict__ Wih_low, const float* __restrict__ Whh_low_f,
                       const float* __restrict__ Wih_high_f, const float* __restrict__ Whh_high_f,
                       const float* __restrict__ Wdec0_f, const float* __restrict__ Wdec1_f,
                       unsigned short* __restrict__ W0, unsigned short* __restrict__ Wlh,
                       unsigned short* __restrict__ Whhl, unsigned short* __restrict__ Wihh,
                       unsigned short* __restrict__ Whhh, unsigned short* __restrict__ Wd0,
                       unsigned short* __restrict__ Wd1, unsigned short* __restrict__ E,
                       float* __restrict__ mask, unsigned* __restrict__ stepflag,
                       unsigned* __restrict__ bar)
{
  int gid = blockIdx.x*blockDim.x + threadIdx.x;
  int gsz = gridDim.x*blockDim.x;
  for (int i=gid; i<2048*512; i+=gsz){
    int r = i>>9, c = i&511;
    W0[i]   = f2bf(Wih_low[(size_t)r*1024 + c]);
    Wlh[i]  = f2bf(Wih_low[(size_t)r*1024 + 512 + c]);
    Whhl[i] = f2bf(Whh_low_f[i]);
    Wihh[i] = f2bf(Wih_high_f[i]);
    Whhh[i] = f2bf(Whh_high_f[i]);
    Wd0[i]  = f2bf(Wdec0_f[i]);
  }
  for (int i=gid; i<512*512; i+=gsz) Wd1[i] = f2bf(Wdec1_f[i]);
  int mt = mtok[0];
  for (int i=gid; i<T_*B_*512; i+=gsz){
    int m = i>>9, k = i&511;
    int t = m>>6, b = m&63;
    float v;
    if (k < 256) v = emb0[(size_t)in0[b*T_+t]*256 + k];
    else         v = emb1[(size_t)in1[b*T_+t]*256 + (k-256)];
    E[i] = f2bf(v);
  }
  for (int i=gid; i<T_*B_; i+=gsz){
    int t = i>>6, b = i&63;
    mask[i] = (in0[b*T_+t] == mt) ? 1.0f : 0.0f;
  }
  for (int i=gid; i<T_; i+=gsz){
    unsigned f = 0;
    for (int b=0;b<B_;b++) f |= (in0[b*T_+i] == mt) ? 1u : 0u;
    stepflag[i] = f;
  }
  for (int i=gid; i<1024; i+=gsz) bar[i] = 0;   // per-WG flag slots (stride 32 u32)
}

// ---------------- bf16 MFMA GEMM: out[M,N] = A[M,512] @ W[N,512]^T + bias ----------------
__launch_bounds__(256)
__global__ void k_gemm(const unsigned short* __restrict__ A,
                       const unsigned short* __restrict__ W,
                       const float* __restrict__ bias1, const float* __restrict__ bias2,
                       unsigned short* __restrict__ out16, float* __restrict__ out32,
                       int N, int mode)
{
  __shared__ unsigned short As[128*40];
  __shared__ unsigned short Bs[128*40];
  const int tid = threadIdx.x;
  const int m0 = blockIdx.x*128, n0 = blockIdx.y*128;
  const int wid = tid>>6, lane = tid&63;
  const int wm = (wid>>1)*64, wn = (wid&1)*64;
  const int lr = lane&15, lk = lane>>4;
  f32x4 acc[4][4] = {};
  for (int k0=0; k0<512; k0+=32){
    __syncthreads();
    #pragma unroll
    for (int i=0;i<2;i++){
      int eb = tid + 256*i;
      int row = eb>>2, kb = eb&3;
      *(bf16x8*)&As[row*40 + kb*8] = *(const bf16x8*)&A[(size_t)(m0+row)*512 + k0 + kb*8];
      *(bf16x8*)&Bs[row*40 + kb*8] = *(const bf16x8*)&W[(size_t)(n0+row)*512 + k0 + kb*8];
    }
    __syncthreads();
    bf16x8 af[4], bff[4];
    #pragma unroll
    for (int i=0;i<4;i++){
      af[i]  = *(const bf16x8*)&As[(wm + i*16 + lr)*40 + lk*8];
      bff[i] = *(const bf16x8*)&Bs[(wn + i*16 + lr)*40 + lk*8];
    }
    #pragma unroll
    for (int mi=0;mi<4;mi++)
      #pragma unroll
      for (int ni=0;ni<4;ni++)
        acc[mi][ni] = __builtin_amdgcn_mfma_f32_16x16x32_bf16(af[mi], bff[ni], acc[mi][ni], 0,0,0);
  }
  #pragma unroll
  for (int mi=0;mi<4;mi++){
    #pragma unroll
    for (int ni=0;ni<4;ni++){
      int n = n0 + wn + ni*16 + lr;
      float bb = bias1 ? bias1[n] : 0.0f;
      if (bias2) bb += bias2[n];
      #pragma unroll
      for (int r=0;r<4;r++){
        int m = m0 + wm + mi*16 + lk*4 + r;
        float v = acc[mi][ni][r] + bb;
        if (mode == 0){
          out16[(size_t)m*N + n] = f2bf(v);
        } else {
          int t = m>>6, b = m&63;
          out32[((size_t)b*T_ + t)*N + n] = v;
        }
      }
    }
  }
}

// ---------------- all-flags barrier: no RMW round trip on the chain ----------------
// arrive: __syncthreads drains this WG's (coherence-point) stores, then lane 0
// fire-and-forgets this WG's OWN flag word (own cacheline: no write contention,
// no returned value -> no round trip on the issuing wave's critical path).
// wait: the 64 lanes of wave 0 poll all 32 flags IN PARALLEL (one load latency
// covers every producer) and ballot-reduce.
__device__ __forceinline__ void g_arrive(unsigned* flags, int j, unsigned gen){
  __syncthreads();
  if (threadIdx.x == 0)
    __hip_atomic_store(&flags[j*32], gen+1u, __ATOMIC_RELAXED, __HIP_MEMORY_SCOPE_AGENT);
  __builtin_amdgcn_sched_barrier(0);
}
__device__ __forceinline__ void g_wait(const unsigned* flags, unsigned gen){
  if (threadIdx.x < 64){
    int l = threadIdx.x;
    for(;;){
      unsigned v = (l < NWG) ? __hip_atomic_load(&flags[l*32], __ATOMIC_RELAXED, __HIP_MEMORY_SCOPE_AGENT)
                             : 0xffffffffu;
      if (__ballot(v >= gen+1u) == ~0ull) break;
      __builtin_amdgcn_s_sleep(1);
    }
  }
  __builtin_amdgcn_sched_barrier(0);
  __syncthreads();
  __builtin_amdgcn_sched_barrier(0);
}

// hht[b][n] = Wlh_rows(n) . h_h[b,:]  (cached, recomputed only on flagged steps)
__device__ __forceinline__ void compute_hht(const unsigned short* __restrict__ hh,
                                            const unsigned short* __restrict__ Wlh,
                                            float* hht, int d0, int mb, int lr, int lk)
{
  bf16x8 av[16];
  #pragma unroll
  for (int ks=0;ks<16;ks++)
    av[ks] = ld_h8(&hh[(mb+lr)*512 + ks*32 + lk*8]);
  f32x4 a[4] = {};
  #pragma unroll
  for (int ks=0;ks<16;ks++){
    #pragma unroll
    for (int g=0; g<4; g++){
      bf16x8 bg = *(const bf16x8*)&Wlh[(size_t)(g*512 + d0 + lr)*512 + ks*32 + lk*8];
      a[g] = __builtin_amdgcn_mfma_f32_16x16x32_bf16(av[ks], bg, a[g], 0,0,0);
    }
  }
  #pragma unroll
  for (int g=0; g<4; g++)
    #pragma unroll
    for (int r=0;r<4;r++){
      int b = mb + lk*4 + r;
      hht[b*68 + g*16 + lr] = a[g][r];
    }
}

// ---------------- persistent recurrence: 32 WGs, WG j owns h-dims [16j, 16j+16) ----------------
__launch_bounds__(256)
__global__ void k_recur(const float* __restrict__ h_low0, const float* __restrict__ c_low0,
                        const float* __restrict__ h_high0, const float* __restrict__ c_high0,
                        const float* __restrict__ bih_high, const float* __restrict__ bhh_high,
                        const unsigned short* __restrict__ xW,
                        const unsigned short* __restrict__ Whhl,
                        const unsigned short* __restrict__ Wlh,
                        const unsigned short* __restrict__ Wihh,
                        const unsigned short* __restrict__ Whhh,
                        const float* __restrict__ mask, const unsigned* __restrict__ stepflag,
                        unsigned short* __restrict__ hl_buf, unsigned short* __restrict__ hh_buf,
                        unsigned short* __restrict__ hseq, unsigned* bar,
                        float* __restrict__ outS)
{
  __shared__ unsigned short Ws[64*520];   // Whh_low slice (64 gate rows), LDS-resident
  __shared__ float hht[64*68];            // cached W_lh @ h_h term
  __shared__ float gb[64*68];             // gate staging
  __shared__ float cl[64*16];
  __shared__ float ch[64*16];
  const int tid = threadIdx.x;
  const int j = blockIdx.x;
  const int d0 = j*16;
  const int wid = tid>>6, lane = tid&63;
  const int lr = lane&15, lk = lane>>4;
  const int mb = wid*16;
  const int eb = tid>>2;            // batch for elementwise
  const int ep = (tid&3)*4;         // 4 dims per thread

  for (int i=tid; i<64*64; i+=256){
    int n = i>>6, cb = i&63;
    int grow = (n>>4)*512 + d0 + (n&15);
    *(bf16x8*)&Ws[n*520 + cb*8] = *(const bf16x8*)&Whhl[(size_t)grow*512 + cb*8];
  }
  for (int i=tid; i<1024; i+=256){
    int b=i>>4, dd=i&15;
    cl[i] = c_low0[b*512 + d0 + dd];
    ch[i] = c_high0[b*512 + d0 + dd];
  }
  {
    int gi = eb*512 + d0 + ep;
    st_h4(&hl_buf[gi], f2bf(h_low0[gi]), f2bf(h_low0[gi+1]), f2bf(h_low0[gi+2]), f2bf(h_low0[gi+3]));
    st_h4(&hh_buf[gi], f2bf(h_high0[gi]), f2bf(h_high0[gi+1]), f2bf(h_high0[gi+2]), f2bf(h_high0[gi+3]));
  }
  unsigned gen = 0;
  g_arrive(bar, j, gen);
  // prefetch xW[0] between arrive and wait: HBM latency hides under the spin
  unsigned long long uxi, uxf, uxg, uxo;
  {
    size_t xr = ((size_t)0*64 + eb)*2048 + d0 + ep;
    uxi = *(const unsigned long long*)&xW[xr];
    uxf = *(const unsigned long long*)&xW[xr + 512];
    uxg = *(const unsigned long long*)&xW[xr + 1024];
    uxo = *(const unsigned long long*)&xW[xr + 1536];
  }
  __builtin_amdgcn_sched_barrier(0);
  g_wait(bar, gen); gen++;
  compute_hht(hh_buf, Wlh, hht, d0, mb, lr, lk);
  __syncthreads();

  int hs = 0;
  for (int t=0; t<T_; t++){
    const int rl = t&1, wl = rl^1;
    const unsigned short* hlr = hl_buf + rl*32768;
    // ---- phase A: low cell ----
    bf16x8 av[16];
    #pragma unroll
    for (int ks=0;ks<16;ks++)
      av[ks] = ld_h8(&hlr[(mb+lr)*512 + ks*32 + lk*8]);
    f32x4 a[4] = {};
    #pragma unroll
    for (int ks=0;ks<16;ks++){
      #pragma unroll
      for (int g=0; g<4; g++){
        bf16x8 bg = *(const bf16x8*)&Ws[(g*16+lr)*520 + ks*32 + lk*8];
        a[g] = __builtin_amdgcn_mfma_f32_16x16x32_bf16(av[ks], bg, a[g], 0,0,0);
      }
    }
    #pragma unroll
    for (int g=0; g<4; g++)
      #pragma unroll
      for (int r=0;r<4;r++){
        int b = mb + lk*4 + r;
        gb[b*68 + g*16 + lr] = a[g][r] + hht[b*68 + g*16 + lr];
      }
    __syncthreads();
    {
      const int b = eb;
      unsigned short hb[4];
      #pragma unroll
      for (int q=0;q<4;q++){
        int dd = ep + q;
        float g_i = gb[b*68 + dd]      + bf2f((unsigned short)(uxi >> (16*q)));
        float g_f = gb[b*68 + 16 + dd] + bf2f((unsigned short)(uxf >> (16*q)));
        float g_g = gb[b*68 + 32 + dd] + bf2f((unsigned short)(uxg >> (16*q)));
        float g_o = gb[b*68 + 48 + dd] + bf2f((unsigned short)(uxo >> (16*q)));
        float c = sigm(g_f)*cl[b*16+dd] + sigm(g_i)*tanhf(g_g);
        float h = sigm(g_o)*tanhf(c);
        cl[b*16+dd] = c;
        hb[q] = f2bf(h);
      }
      st_h4(&hl_buf[wl*32768 + b*512 + d0 + ep], hb[0], hb[1], hb[2], hb[3]);
      unsigned long long hp = (unsigned long long)hb[0] | ((unsigned long long)hb[1]<<16)
                            | ((unsigned long long)hb[2]<<32) | ((unsigned long long)hb[3]<<48);
      *(unsigned long long*)&hseq[((size_t)t*64 + b)*512 + d0 + ep] = hp;
    }
    g_arrive(bar, j, gen);
    // prefetch next step's xW between arrive and wait (latency under the spin)
    if (t+1 < T_){
      size_t xr = ((size_t)(t+1)*64 + eb)*2048 + d0 + ep;
      uxi = *(const unsigned long long*)&xW[xr];
      uxf = *(const unsigned long long*)&xW[xr + 512];
      uxg = *(const unsigned long long*)&xW[xr + 1024];
      uxo = *(const unsigned long long*)&xW[xr + 1536];
    }
    __builtin_amdgcn_sched_barrier(0);
    g_wait(bar, gen); gen++;
    // ---- phase B: high cell (only ~8/256 steps) ----
    if (stepflag[t]){
      const unsigned short* hln = hl_buf + wl*32768;
      const unsigned short* hhr = hh_buf + hs*32768;
      bf16x8 avl[16], avh[16];
      #pragma unroll
      for (int ks=0;ks<16;ks++){
        avl[ks] = ld_h8(&hln[(mb+lr)*512 + ks*32 + lk*8]);
        avh[ks] = ld_h8(&hhr[(mb+lr)*512 + ks*32 + lk*8]);
      }
      f32x4 hacc[4] = {};
      #pragma unroll
      for (int ks=0;ks<16;ks++){
        #pragma unroll
        for (int g=0; g<4; g++){
          size_t grw = (size_t)(g*512 + d0 + lr)*512 + ks*32 + lk*8;
          bf16x8 bi = *(const bf16x8*)&Wihh[grw];
          bf16x8 bh = *(const bf16x8*)&Whhh[grw];
          hacc[g] = __builtin_amdgcn_mfma_f32_16x16x32_bf16(avl[ks], bi, hacc[g], 0,0,0);
          hacc[g] = __builtin_amdgcn_mfma_f32_16x16x32_bf16(avh[ks], bh, hacc[g], 0,0,0);
        }
      }
      #pragma unroll
      for (int g=0; g<4; g++)
        #pragma unroll
        for (int r=0;r<4;r++){
          int b = mb + lk*4 + r;
          gb[b*68 + g*16 + lr] = hacc[g][r];
        }
      __syncthreads();
      {
        const int b = eb;
        float m = mask[t*64 + b];
        unsigned long long hold4 = ld_h4(&hh_buf[hs*32768 + b*512 + d0 + ep]);
        unsigned short hn[4];
        #pragma unroll
        for (int q=0;q<4;q++){
          int dd = ep + q; int d = d0 + dd;
          float g_i = gb[b*68+dd]      + bih_high[d]      + bhh_high[d];
          float g_f = gb[b*68+16+dd]   + bih_high[512+d]  + bhh_high[512+d];
          float g_g = gb[b*68+32+dd]   + bih_high[1024+d] + bhh_high[1024+d];
          float g_o = gb[b*68+48+dd]   + bih_high[1536+d] + bhh_high[1536+d];
          float ct = sigm(g_f)*ch[b*16+dd] + sigm(g_i)*tanhf(g_g);
          float ht = sigm(g_o)*tanhf(ct);
          float hold = bf2f((unsigned short)(hold4 >> (16*q)));
          hn[q] = f2bf(m*ht + (1.0f-m)*hold);
          ch[b*16+dd] = m*ct + (1.0f-m)*ch[b*16+dd];
        }
        st_h4(&hh_buf[(hs^1)*32768 + b*512 + d0 + ep], hn[0], hn[1], hn[2], hn[3]);
      }
      g_arrive(bar, j, gen);
      g_wait(bar, gen); gen++;
      hs ^= 1;
      compute_hht(hh_buf + hs*32768, Wlh, hht, d0, mb, lr, lk);
      __syncthreads();
    }
  }
  // final states -> f32 (h_l in slot 0 after t=255)
  {
    int gi = eb*512 + d0 + ep;
    unsigned long long hl4 = ld_h4(&hl_buf[gi]);
    unsigned long long hh4 = ld_h4(&hh_buf[hs*32768 + gi]);
    #pragma unroll
    for (int q=0;q<4;q++){
      outS[gi+q]           = bf2f((unsigned short)(hl4 >> (16*q)));
      outS[32768 + gi + q] = cl[eb*16 + ep + q];
      outS[65536 + gi + q] = bf2f((unsigned short)(hh4 >> (16*q)));
      outS[98304 + gi + q] = ch[eb*16 + ep + q];
    }
  }
}

extern "C" void kernel_launch(void* const* d_in, const int* in_sizes, int n_in,
                              void* d_out, int out_size, void* d_ws, size_t ws_size,
                              hipStream_t stream)
{
  const int*   in0    = (const int*)  d_in[0];
  const int*   in1    = (const int*)  d_in[1];
  const float* hl0    = (const float*)d_in[2];
  const float* cl0    = (const float*)d_in[3];
  const float* hh0    = (const float*)d_in[4];
  const float* ch0    = (const float*)d_in[5];
  const int*   mtok   = (const int*)  d_in[6];
  const float* emb0   = (const float*)d_in[7];
  const float* emb1   = (const float*)d_in[8];
  const float* Wihl_f = (const float*)d_in[9];
  const float* bihl   = (const float*)d_in[10];
  const float* Whhl_f = (const float*)d_in[11];
  const float* bhhl   = (const float*)d_in[12];
  const float* Wihh_f = (const float*)d_in[13];
  const float* bihh   = (const float*)d_in[14];
  const float* Whhh_f = (const float*)d_in[15];
  const float* bhhh   = (const float*)d_in[16];
  const float* Wd0_f  = (const float*)d_in[17];
  const float* bd0    = (const float*)d_in[18];
  const float* Wd1_f  = (const float*)d_in[19];
  const float* bd1    = (const float*)d_in[20];

  // d_out is FLOAT. Layout (floats): dec0 [B,T,2048] @0, dec1 [B,T,512] @33554432,
  // states @41943040 (4 x 32768).
  float* dout = (float*)d_out;
  // bf16 scratch aliased into d_out (dead before the dec GEMMs write there)
  unsigned short* xW = (unsigned short*)dout;              // 64 MiB in dec0 region
  unsigned short* E  = (unsigned short*)(dout + 33554432); // 16 MiB in dec1 region

  char* ws = (char*)d_ws;
  unsigned short* hseq = (unsigned short*)(ws + 0);          // [16384][512] bf16, 16 MiB
  unsigned short* W0   = (unsigned short*)(ws + 16777216);
  unsigned short* Wlh  = (unsigned short*)(ws + 18874368);
  unsigned short* Whhl = (unsigned short*)(ws + 20971520);
  unsigned short* Wihh = (unsigned short*)(ws + 23068672);
  unsigned short* Whhh = (unsigned short*)(ws + 25165824);
  unsigned short* Wd0  = (unsigned short*)(ws + 27262976);
  unsigned short* Wd1  = (unsigned short*)(ws + 29360128);
  unsigned short* hlb  = (unsigned short*)(ws + 29884416);   // [2][64][512] bf16
  unsigned short* hhb  = (unsigned short*)(ws + 30015488);   // [2][64][512] bf16
  float*          mask = (float*)    (ws + 30146560);        // [256][64]
  unsigned*       sflg = (unsigned*) (ws + 30212096);        // [256]
  unsigned*       bar  = (unsigned*) (ws + 30213120);        // flags[32*32] u32

  k_prep<<<2048, 256, 0, stream>>>(in0,in1,mtok,emb0,emb1,Wihl_f,Whhl_f,Wihh_f,Whhh_f,Wd0_f,Wd1_f,
                                   W0,Wlh,Whhl,Wihh,Whhh,Wd0,Wd1,E,mask,sflg,bar);
  dim3 g1(128,16);
  k_gemm<<<g1, 256, 0, stream>>>(E, W0, bihl, bhhl, xW, nullptr, 2048, 0);
  k_recur<<<NWG, 256, 0, stream>>>(hl0,cl0,hh0,ch0,bihh,bhhh,xW,Whhl,Wlh,Wihh,Whhh,
                                   mask,sflg,hlb,hhb,hseq,bar,dout + 41943040);
  k_gemm<<<g1, 256, 0, stream>>>(hseq, Wd0, bd0, nullptr, nullptr, dout, 2048, 1);
  dim3 g2(128,4);
  k_gemm<<<g2, 256, 0, stream>>>(hseq, Wd1, bd1, nullptr, nullptr, dout + 33554432, 512, 1);
}